// Round 4
// baseline (369.408 us; speedup 1.0000x reference)
//
#include <hip/hip_runtime.h>

typedef unsigned short u16;
typedef __bf16 bf16x8 __attribute__((ext_vector_type(8)));
typedef float  fx4    __attribute__((ext_vector_type(4)));
typedef unsigned int u32x4 __attribute__((ext_vector_type(4)));

__device__ __forceinline__ u16 f2bf(float f) {
    unsigned int x = __builtin_bit_cast(unsigned int, f);
    x = x + 0x7fffu + ((x >> 16) & 1u);   // round-to-nearest-even
    return (u16)(x >> 16);
}
__device__ __forceinline__ __bf16 f2bf16(float f) {
    return __builtin_bit_cast(__bf16, f2bf(f));
}
// native RNE f32->bf16
__device__ __forceinline__ u16 f2bf_fast(float f) {
    return __builtin_bit_cast(u16, (__bf16)f);
}
__device__ __forceinline__ float exp2_fast(float x) {
#if __has_builtin(__builtin_amdgcn_exp2f)
    return __builtin_amdgcn_exp2f(x);
#else
    float r;
    __asm__ volatile("v_exp_f32 %0, %1" : "=v"(r) : "v"(x));
    return r;
#endif
}
// streaming (evict-first) 16-B load: native clang vector type (HIP uint4 is a
// class and is rejected by __builtin_nontemporal_load)
__device__ __forceinline__ u32x4 ld_nt4(const int* p) {
    return __builtin_nontemporal_load((const u32x4*)p);
}

#define MFMA16(a, b, c) __builtin_amdgcn_mfma_f32_16x16x32_bf16((a), (b), (c), 0, 0, 0)
// wave-private LDS write->read ordering (DS ops are in-order per wave)
#define WAVE_LDS_SYNC() __asm__ volatile("s_waitcnt lgkmcnt(0)" ::: "memory")

// ---------------------------------------------------------------------------
// Kernel A: WT[p][c][k] = bf16(W_p[k][c])  -> stored in first 96 KB of d_out
// ---------------------------------------------------------------------------
__global__ __launch_bounds__(256) void wt_kernel(
    const float* __restrict__ Wq, const float* __restrict__ Wk,
    const float* __restrict__ Wv, u16* __restrict__ WT)
{
    const int o = blockIdx.x * 256 + threadIdx.x;     // 0..49151
    const int p = o >> 14, rem = o & 16383, c = rem >> 7, k = rem & 127;
    const float* W = (p == 0) ? Wq : ((p == 1) ? Wk : Wv);
    WT[o] = f2bf(W[k * 128 + c]);
}

// ---------------------------------------------------------------------------
// Kernel B: Q, K, V^T fragment-major. Results staged per-wave in LDS in
// fragment layout (scattered 2-B LDS writes are cheap), then written to global
// with fully-coalesced uint4 stores instead of 48 scattered 2-B global stores.
// ---------------------------------------------------------------------------
__global__ __launch_bounds__(256, 2) void qkv_kernel(
    const float* __restrict__ X, const u16* __restrict__ WT,
    const float* __restrict__ bq, const float* __restrict__ bk,
    const float* __restrict__ bv,
    u16* __restrict__ Qf, u16* __restrict__ Kf, u16* __restrict__ Vf)
{
    __shared__ __align__(16) u16 st[4][1024];   // 2 KB per wave staging

    const int tid  = threadIdx.x;
    const int w    = tid >> 6;
    const int lane = tid & 63;
    const int n    = lane & 15;
    const int quad = lane >> 4;
    const int gw   = blockIdx.x * 4 + w;   // 0..2047
    const int rt   = gw >> 1, ch = gw & 1;
    const int row0 = rt * 16;
    const int b    = row0 >> 11;
    const int keyb = row0 & 2047;          // multiple of 16

    u16* sw = st[w];

    // X fragments: lane holds X[row0+n][kk*32 + quad*8 + j]  (fp32 -> bf16).
    bf16x8 af[4];
    {
        const float* xr = X + (size_t)(row0 + n) * 128;
#pragma unroll
        for (int kk = 0; kk < 4; ++kk) {
            float4 f0 = *(const float4*)(xr + kk * 32 + quad * 8);
            float4 f1 = *(const float4*)(xr + kk * 32 + quad * 8 + 4);
            bf16x8 a;
            a[0] = f2bf16(f0.x); a[1] = f2bf16(f0.y); a[2] = f2bf16(f0.z); a[3] = f2bf16(f0.w);
            a[4] = f2bf16(f1.x); a[5] = f2bf16(f1.y); a[6] = f2bf16(f1.z); a[7] = f2bf16(f1.w);
            af[kk] = a;
        }
    }

    // ---- Q and K (LDS-staged, coalesced store)
    const float* Bs[2] = {bq, bk};
#pragma unroll
    for (int p = 0; p < 2; ++p) {
        const u16* wt = WT + p * 16384;
#pragma unroll
        for (int nt = 0; nt < 4; ++nt) {
            const int col0 = ch * 64 + nt * 16;
            fx4 acc = {0.f, 0.f, 0.f, 0.f};
#pragma unroll
            for (int kk = 0; kk < 4; ++kk) {
                bf16x8 bf = __builtin_bit_cast(bf16x8,
                    *(const uint4*)&wt[(col0 + n) * 128 + kk * 32 + quad * 8]);
                acc = MFMA16(af[kk], bf, acc);
            }
            const float bb = Bs[p][col0 + n];
            const int c = col0 + n;
            // local fragment index within this wave's 1024-u16 span
            const int li = ((c >> 5) & 1) * 512 + ((c >> 3) & 3) * 128 + (c & 7);
#pragma unroll
            for (int r = 0; r < 4; ++r)
                sw[li + (quad * 4 + r) * 8] = f2bf(acc[r] + bb);
        }
        WAVE_LDS_SYNC();
        u16* gbase;
        if (p == 0) {
            gbase = Qf + (((size_t)(b * 128 + (keyb >> 4)) * 4 + 2 * ch) << 9);
        } else {
            gbase = Kf + (((size_t)((b * 64 + (keyb >> 5)) * 2 + ((keyb >> 4) & 1)) * 4 + 2 * ch) << 9);
        }
        *(uint4*)(gbase + lane * 8)       = *(const uint4*)(sw + lane * 8);
        *(uint4*)(gbase + 512 + lane * 8) = *(const uint4*)(sw + 512 + lane * 8);
    }

    // ---- V^T[d][key]  (operand-swapped MFMA), LDS-staged
    {
        const u16* wtv = WT + 2 * 16384;
        const int hk    = (keyb >> 4) & 1;
        const int vtile = keyb >> 5;
#pragma unroll
        for (int d0 = 0; d0 < 4; ++d0) {
            const int dbase = ch * 64 + d0 * 16;
            fx4 acc = {0.f, 0.f, 0.f, 0.f};
#pragma unroll
            for (int kk = 0; kk < 4; ++kk) {
                bf16x8 wf = __builtin_bit_cast(bf16x8,
                    *(const uint4*)&wtv[(dbase + n) * 128 + kk * 32 + quad * 8]);
                acc = MFMA16(wf, af[kk], acc);
            }
            const int li = d0 * 256 + ((n >> 3) & 1) * 128 + (n & 7);
#pragma unroll
            for (int r = 0; r < 4; ++r)
                sw[li + (quad * 4 + r) * 8] = f2bf(acc[r] + bv[dbase + quad * 4 + r]);
        }
        WAVE_LDS_SYNC();
        const int l5 = lane >> 5, lo = lane & 31;
#pragma unroll
        for (int i = 0; i < 2; ++i) {
            const int c2 = l5 + 2 * i;
            u16* g = Vf + (((size_t)(b * 64 + vtile) * 8 + ch * 4 + c2) << 9)
                        + hk * 256 + lo * 8;
            *(uint4*)g = *(const uint4*)(sw + c2 * 256 + lo * 8);
        }
    }
}

// ---------------------------------------------------------------------------
// Kernel C: fused masked attention. The adjacency stream (the HBM compulsory
// traffic) is loaded as 2x 16-B nt loads per lane into a double-buffered LDS
// stage, pipelined 2 tiles deep -> ~64 KB outstanding HBM bytes per CU
// (vs ~512 B with scalar loads) so the adj fetch runs at HBM BW instead of
// latency-bound ~1 TB/s. Stage reads XOR-swizzled -> 2-way (free). The stage
// aliases the first 16 KB of mO (epilogue-only), guarded by __syncthreads().
// ---------------------------------------------------------------------------
__global__ __launch_bounds__(256, 4) void attn_kernel(
    const u16* __restrict__ Qf, const u16* __restrict__ Kf,
    const u16* __restrict__ Vf, const int* __restrict__ adj,
    float* __restrict__ out)
{
    __shared__ __align__(16) float mO[4][16 * 128];  // 32 KB (first 16 KB = adj stage in loop)
    __shared__ __align__(16) float ml[4][16];        // per-wave row sums
    __shared__ __align__(16) u16 pl[4][640];         // per-wave P, stride 40

    int* adjst = (int*)&mO[0][0];                    // [h][buf(2)][512] ints

    const int tid  = threadIdx.x;
    const int h    = tid >> 6;                       // key-quarter
    const int lane = tid & 63;
    const int n    = lane & 15;
    const int quad = lane >> 4;
    const int b    = blockIdx.x & 7;
    const int qt   = blockIdx.x >> 3;                // 0..127
    const int q0   = qt * 16;
    const size_t bN = (size_t)b * 2048;

    // adj staging lane roles: row rr (0..15), 8-int col group c4
    const int rr = lane >> 2;
    const int c4 = (lane & 3) * 8;
    const int sx = quad << 3;                        // XOR swizzle (row-group dependent)
    const int* agl = adj + (((size_t)(bN + q0 + rr)) << 11) + h * 512 + c4;

    // Q fragments (A-layout): 4 coalesced 1 KB loads
    bf16x8 qf[4];
    {
        const u16* qp = Qf + ((size_t)(b * 128 + qt) << 11) + lane * 8;
#pragma unroll
        for (int kk = 0; kk < 4; ++kk)
            qf[kk] = __builtin_bit_cast(bf16x8, *(const uint4*)(qp + (kk << 9)));
    }
    const u16* Kb = Kf + ((size_t)b << 18);
    const u16* Vb = Vf + ((size_t)b << 18);

    fx4 O[8];
#pragma unroll
    for (int i = 0; i < 8; ++i) O[i] = (fx4){0.f, 0.f, 0.f, 0.f};
    fx4 Lacc = {0.f, 0.f, 0.f, 0.f};                 // row sums via MFMA-ones

    bf16x8 ONESF;
    {
        const __bf16 one = __builtin_bit_cast(__bf16, (u16)0x3F80);
#pragma unroll
        for (int j = 0; j < 8; ++j) ONESF[j] = one;
    }

    const float C2 = 0.12751742f;   // (1/sqrt(128)) * log2(e)
    const float MB = -14427.0f;     // -10000 * log2(e): exp2 -> exactly 0.0
    u16* pw = pl[h];

    // ---- adj pipeline prologue: tiles 0 and 1 in regs; tile 0 -> buf0
    u32x4 rA0, rA1, rB0, rB1;
    rA0 = ld_nt4(agl + 0);  rA1 = ld_nt4(agl + 4);    // tile 0
    rB0 = ld_nt4(agl + 32); rB1 = ld_nt4(agl + 36);   // tile 1
    {
        int* sw0 = adjst + h * 1024 + rr * 32 + (c4 ^ sx);
        *(u32x4*)sw0       = rA0;
        *((u32x4*)sw0 + 1) = rA1;
    }

#define TILE_BODY(T, RA0_, RA1_, RB0_, RB1_, DO_ISSUE, DO_WRITE)                    \
  {                                                                                 \
    const int tg = h * 16 + (T);                                                    \
    const u16* kt_ = Kb + ((size_t)tg << 12) + lane * 8;                            \
    const u16* vt_ = Vb + ((size_t)tg << 12) + lane * 8;                            \
    bf16x8 kb[8]; bf16x8 vv[8];                                                     \
    _Pragma("unroll") for (int kk = 0; kk < 8; ++kk)                                \
      kb[kk] = __builtin_bit_cast(bf16x8, *(const uint4*)(kt_ + (kk << 9)));        \
    _Pragma("unroll") for (int dt = 0; dt < 8; ++dt)                                \
      vv[dt] = __builtin_bit_cast(bf16x8, *(const uint4*)(vt_ + (dt << 9)));        \
    if (DO_ISSUE) {                                                                 \
      RA0_ = ld_nt4(agl + ((T) + 2) * 32);                                          \
      RA1_ = ld_nt4(agl + ((T) + 2) * 32 + 4);                                      \
    }                                                                               \
    fx4 S0 = {0.f, 0.f, 0.f, 0.f}, S1 = {0.f, 0.f, 0.f, 0.f};                       \
    _Pragma("unroll") for (int kk = 0; kk < 4; ++kk) {                              \
      S0 = MFMA16(qf[kk], kb[kk], S0);                                              \
      S1 = MFMA16(qf[kk], kb[4 + kk], S1);                                          \
    }                                                                               \
    WAVE_LDS_SYNC();                                                                \
    const int* sr = adjst + h * 1024 + ((T) & 1) * 512;                             \
    _Pragma("unroll") for (int r = 0; r < 4; ++r) {                                 \
      const int a0 = sr[(quad * 4 + r) * 32 + (n ^ sx)];                            \
      const int a1 = sr[(quad * 4 + r) * 32 + ((16 + n) ^ sx)];                     \
      const float e0 = exp2_fast(__builtin_fmaf(S0[r], C2, a0 ? 0.f : MB));         \
      const float e1 = exp2_fast(__builtin_fmaf(S1[r], C2, a1 ? 0.f : MB));         \
      pw[(quad * 4 + r) * 40 + n]      = f2bf_fast(e0);                             \
      pw[(quad * 4 + r) * 40 + 16 + n] = f2bf_fast(e1);                             \
    }                                                                               \
    WAVE_LDS_SYNC();                                                                \
    bf16x8 pf = __builtin_bit_cast(bf16x8, *(const uint4*)&pw[n * 40 + quad * 8]);  \
    _Pragma("unroll") for (int dt = 0; dt < 8; ++dt)                                \
      O[dt] = MFMA16(pf, vv[dt], O[dt]);                                            \
    Lacc = MFMA16(pf, ONESF, Lacc);                                                 \
    if (DO_WRITE) {                                                                 \
      int* sw_ = adjst + h * 1024 + (((T) + 1) & 1) * 512 + rr * 32 + (c4 ^ sx);    \
      *(u32x4*)sw_       = RB0_;                                                    \
      *((u32x4*)sw_ + 1) = RB1_;                                                    \
    }                                                                               \
  }

    for (int tt = 0; tt < 16; tt += 2) {
        TILE_BODY(tt,     rA0, rA1, rB0, rB1, (tt < 14), 1);
        TILE_BODY(tt + 1, rB0, rB1, rA0, rA1, (tt < 13), (tt < 14));
    }
#undef TILE_BODY

    // all waves done with adjst (aliases mO) before epilogue writes
    __syncthreads();

    // ---- 4-way merge across key-quarters, ELU, store
#pragma unroll
    for (int r = 0; r < 4; ++r) {
        const int row = quad * 4 + r;
        if (n == 0) ml[h][row] = Lacc[r];
#pragma unroll
        for (int dt = 0; dt < 8; ++dt)
            mO[h][row * 128 + dt * 16 + n] = O[dt][r];
    }
    __syncthreads();

#pragma unroll
    for (int r = 0; r < 4; ++r) {
        const int row = quad * 4 + r;
        const float L = ml[0][row] + ml[1][row] + ml[2][row] + ml[3][row];
        const float linv = 1.f / L;
        float* po = out + (bN + q0 + row) * 128;
#pragma unroll
        for (int dti = 0; dti < 2; ++dti) {
            const int dt = h * 2 + dti;
            float o = 0.f;
#pragma unroll
            for (int g = 0; g < 4; ++g) o += mO[g][row * 128 + dt * 16 + n];
            const float hh = o * linv;
            po[dt * 16 + n] = (hh > 0.f) ? hh : (__expf(hh) - 1.f);
        }
    }
}

// ---------------------------------------------------------------------------
extern "C" void kernel_launch(void* const* d_in, const int* in_sizes, int n_in,
                              void* d_out, int out_size, void* d_ws, size_t ws_size,
                              hipStream_t stream) {
    (void)in_sizes; (void)n_in; (void)out_size; (void)ws_size;
    const float* X   = (const float*)d_in[0];
    const int*   adj = (const int*)d_in[1];
    const float* Wq  = (const float*)d_in[2];
    const float* bq  = (const float*)d_in[3];
    const float* Wk  = (const float*)d_in[4];
    const float* bk  = (const float*)d_in[5];
    const float* Wv  = (const float*)d_in[6];
    const float* bv  = (const float*)d_in[7];
    float* out = (float*)d_out;

    u16* WT  = (u16*)d_out;                      // 96 KB scratch, overwritten by attn
    u16* Qf  = (u16*)d_ws;                       // 4 MB fragment-major Q
    u16* Kf  = Qf + (size_t)16384 * 128;         // 4 MB fragment-major K
    u16* Vf  = Kf + (size_t)16384 * 128;         // 4 MB fragment-major V^T

    wt_kernel<<<192, 256, 0, stream>>>(Wq, Wk, Wv, WT);
    qkv_kernel<<<512, 256, 0, stream>>>(X, WT, bq, bk, bv, Qf, Kf, Vf);
    attn_kernel<<<1024, 256, 0, stream>>>(Qf, Kf, Vf, adj, out);
}

// Round 5
// 302.833 us; speedup vs baseline: 1.2198x; 1.2198x over previous
//
#include <hip/hip_runtime.h>

typedef unsigned short u16;
typedef __bf16 bf16x8 __attribute__((ext_vector_type(8)));
typedef float  fx4    __attribute__((ext_vector_type(4)));

__device__ __forceinline__ u16 f2bf(float f) {
    unsigned int x = __builtin_bit_cast(unsigned int, f);
    x = x + 0x7fffu + ((x >> 16) & 1u);   // round-to-nearest-even
    return (u16)(x >> 16);
}
__device__ __forceinline__ __bf16 f2bf16(float f) {
    return __builtin_bit_cast(__bf16, f2bf(f));
}
// native RNE f32->bf16
__device__ __forceinline__ u16 f2bf_fast(float f) {
    return __builtin_bit_cast(u16, (__bf16)f);
}
__device__ __forceinline__ float exp2_fast(float x) {
#if __has_builtin(__builtin_amdgcn_exp2f)
    return __builtin_amdgcn_exp2f(x);
#else
    float r;
    __asm__ volatile("v_exp_f32 %0, %1" : "=v"(r) : "v"(x));
    return r;
#endif
}
// streaming (evict-first) int load: keeps adj from evicting K/V out of L2
__device__ __forceinline__ int ld_nt(const int* p) {
    return __builtin_nontemporal_load(p);
}

#define MFMA16(a, b, c) __builtin_amdgcn_mfma_f32_16x16x32_bf16((a), (b), (c), 0, 0, 0)
// wave-private LDS write->read ordering (DS ops are in-order per wave)
#define WAVE_LDS_SYNC() __asm__ volatile("s_waitcnt lgkmcnt(0)" ::: "memory")

// ---------------------------------------------------------------------------
// Kernel A: WT[p][c][k] = bf16(W_p[k][c])  -> stored in first 96 KB of d_out
// ---------------------------------------------------------------------------
__global__ __launch_bounds__(256) void wt_kernel(
    const float* __restrict__ Wq, const float* __restrict__ Wk,
    const float* __restrict__ Wv, u16* __restrict__ WT)
{
    const int o = blockIdx.x * 256 + threadIdx.x;     // 0..49151
    const int p = o >> 14, rem = o & 16383, c = rem >> 7, k = rem & 127;
    const float* W = (p == 0) ? Wq : ((p == 1) ? Wk : Wv);
    WT[o] = f2bf(W[k * 128 + c]);
}

// ---------------------------------------------------------------------------
// Kernel B: Q, K, V^T fragment-major. Results staged per-wave in LDS in
// fragment layout (scattered 2-B LDS writes are cheap), then written to global
// with fully-coalesced uint4 stores instead of 48 scattered 2-B global stores.
// ---------------------------------------------------------------------------
__global__ __launch_bounds__(256, 2) void qkv_kernel(
    const float* __restrict__ X, const u16* __restrict__ WT,
    const float* __restrict__ bq, const float* __restrict__ bk,
    const float* __restrict__ bv,
    u16* __restrict__ Qf, u16* __restrict__ Kf, u16* __restrict__ Vf)
{
    __shared__ __align__(16) u16 st[4][1024];   // 2 KB per wave staging

    const int tid  = threadIdx.x;
    const int w    = tid >> 6;
    const int lane = tid & 63;
    const int n    = lane & 15;
    const int quad = lane >> 4;
    const int gw   = blockIdx.x * 4 + w;   // 0..2047
    const int rt   = gw >> 1, ch = gw & 1;
    const int row0 = rt * 16;
    const int b    = row0 >> 11;
    const int keyb = row0 & 2047;          // multiple of 16

    u16* sw = st[w];

    // X fragments: lane holds X[row0+n][kk*32 + quad*8 + j]  (fp32 -> bf16).
    bf16x8 af[4];
    {
        const float* xr = X + (size_t)(row0 + n) * 128;
#pragma unroll
        for (int kk = 0; kk < 4; ++kk) {
            float4 f0 = *(const float4*)(xr + kk * 32 + quad * 8);
            float4 f1 = *(const float4*)(xr + kk * 32 + quad * 8 + 4);
            bf16x8 a;
            a[0] = f2bf16(f0.x); a[1] = f2bf16(f0.y); a[2] = f2bf16(f0.z); a[3] = f2bf16(f0.w);
            a[4] = f2bf16(f1.x); a[5] = f2bf16(f1.y); a[6] = f2bf16(f1.z); a[7] = f2bf16(f1.w);
            af[kk] = a;
        }
    }

    // ---- Q and K (LDS-staged, coalesced store)
    const float* Bs[2] = {bq, bk};
#pragma unroll
    for (int p = 0; p < 2; ++p) {
        const u16* wt = WT + p * 16384;
#pragma unroll
        for (int nt = 0; nt < 4; ++nt) {
            const int col0 = ch * 64 + nt * 16;
            fx4 acc = {0.f, 0.f, 0.f, 0.f};
#pragma unroll
            for (int kk = 0; kk < 4; ++kk) {
                bf16x8 bf = __builtin_bit_cast(bf16x8,
                    *(const uint4*)&wt[(col0 + n) * 128 + kk * 32 + quad * 8]);
                acc = MFMA16(af[kk], bf, acc);
            }
            const float bb = Bs[p][col0 + n];
            const int c = col0 + n;
            // local fragment index within this wave's 1024-u16 span
            const int li = ((c >> 5) & 1) * 512 + ((c >> 3) & 3) * 128 + (c & 7);
#pragma unroll
            for (int r = 0; r < 4; ++r)
                sw[li + (quad * 4 + r) * 8] = f2bf(acc[r] + bb);
        }
        WAVE_LDS_SYNC();
        u16* gbase;
        if (p == 0) {
            gbase = Qf + (((size_t)(b * 128 + (keyb >> 4)) * 4 + 2 * ch) << 9);
        } else {
            gbase = Kf + (((size_t)((b * 64 + (keyb >> 5)) * 2 + ((keyb >> 4) & 1)) * 4 + 2 * ch) << 9);
        }
        *(uint4*)(gbase + lane * 8)       = *(const uint4*)(sw + lane * 8);
        *(uint4*)(gbase + 512 + lane * 8) = *(const uint4*)(sw + 512 + lane * 8);
    }

    // ---- V^T[d][key]  (operand-swapped MFMA), LDS-staged
    {
        const u16* wtv = WT + 2 * 16384;
        const int hk    = (keyb >> 4) & 1;
        const int vtile = keyb >> 5;
#pragma unroll
        for (int d0 = 0; d0 < 4; ++d0) {
            const int dbase = ch * 64 + d0 * 16;
            fx4 acc = {0.f, 0.f, 0.f, 0.f};
#pragma unroll
            for (int kk = 0; kk < 4; ++kk) {
                bf16x8 wf = __builtin_bit_cast(bf16x8,
                    *(const uint4*)&wtv[(dbase + n) * 128 + kk * 32 + quad * 8]);
                acc = MFMA16(wf, af[kk], acc);
            }
            const int li = d0 * 256 + ((n >> 3) & 1) * 128 + (n & 7);
#pragma unroll
            for (int r = 0; r < 4; ++r)
                sw[li + (quad * 4 + r) * 8] = f2bf(acc[r] + bv[dbase + quad * 4 + r]);
        }
        WAVE_LDS_SYNC();
        const int l5 = lane >> 5, lo = lane & 31;
#pragma unroll
        for (int i = 0; i < 2; ++i) {
            const int c2 = l5 + 2 * i;
            u16* g = Vf + (((size_t)(b * 64 + vtile) * 8 + ch * 4 + c2) << 9)
                        + hk * 256 + lo * 8;
            *(uint4*)g = *(const uint4*)(sw + c2 * 256 + lo * 8);
        }
    }
}

// ---------------------------------------------------------------------------
// Kernel C: fused masked attention, fixed-shift softmax. Round-1 structure
// (proven 92 us warm) with ONE change: __launch_bounds__(256, 3) instead of
// (256, 4). Theory: the 64-VGPR allocation (observed in every round) starves
// memory-level parallelism (few loads in flight per wave -> all pipes ~10%
// busy, latency-bound). Cap 168 VGPRs @ 3 waves/EU matches the occupancy we
// actually measured (38-44%), so no real occupancy is lost.
// ---------------------------------------------------------------------------
__global__ __launch_bounds__(256, 3) void attn_kernel(
    const u16* __restrict__ Qf, const u16* __restrict__ Kf,
    const u16* __restrict__ Vf, const int* __restrict__ adj,
    float* __restrict__ out)
{
    __shared__ __align__(16) float mO[4][16 * 128];  // per-wave O dump (32 KB)
    __shared__ __align__(16) float ml[4][16];        // per-wave row sums
    __shared__ __align__(16) u16 pl[4][640];         // per-wave P, stride 40

    const int tid  = threadIdx.x;
    const int h    = tid >> 6;                       // key-quarter
    const int lane = tid & 63;
    const int n    = lane & 15;
    const int quad = lane >> 4;
    const int b    = blockIdx.x & 7;
    const int qt   = blockIdx.x >> 3;                // 0..127
    const int q0   = qt * 16;
    const size_t bN = (size_t)b * 2048;

    // Q fragments (A-layout): 4 coalesced 1 KB loads
    bf16x8 qf[4];
    {
        const u16* qp = Qf + ((size_t)(b * 128 + qt) << 11) + lane * 8;
#pragma unroll
        for (int kk = 0; kk < 4; ++kk)
            qf[kk] = __builtin_bit_cast(bf16x8, *(const uint4*)(qp + (kk << 9)));
    }
    const u16* Kb = Kf + ((size_t)b << 18);
    const u16* Vb = Vf + ((size_t)b << 18);

    fx4 O[8];
#pragma unroll
    for (int i = 0; i < 8; ++i) O[i] = (fx4){0.f, 0.f, 0.f, 0.f};
    fx4 Lacc = {0.f, 0.f, 0.f, 0.f};                 // row sums via MFMA-ones

    bf16x8 ONESF;
    {
        const __bf16 one = __builtin_bit_cast(__bf16, (u16)0x3F80);
#pragma unroll
        for (int j = 0; j < 8; ++j) ONESF[j] = one;
    }

    const int* adjb = adj + (bN + q0 + quad * 4) * 2048;
    const float C2 = 0.12751742f;   // (1/sqrt(128)) * log2(e)
    const float MB = -14427.0f;     // -10000 * log2(e): exp2 -> exactly 0.0
    u16* pw = pl[h];

    // prologue: adjacency bias (float, exp2 domain) for first tile
    float b0c[4], b1c[4];
    {
        const int k0 = h * 512;
#pragma unroll
        for (int r = 0; r < 4; ++r) {
            b0c[r] = ld_nt(&adjb[(size_t)r * 2048 + k0 + n])      ? 0.f : MB;
            b1c[r] = ld_nt(&adjb[(size_t)r * 2048 + k0 + 16 + n]) ? 0.f : MB;
        }
    }

    for (int t = 0; t < 16; ++t) {
        const int tg = h * 16 + t;
        const u16* kt_ = Kb + ((size_t)tg << 12) + lane * 8;
        const u16* vt_ = Vb + ((size_t)tg << 12) + lane * 8;

        // ---- issue K fragment loads first (S-chain head)
        bf16x8 kb[8];
#pragma unroll
        for (int kk = 0; kk < 8; ++kk)
            kb[kk] = __builtin_bit_cast(bf16x8, *(const uint4*)(kt_ + (kk << 9)));

        // ---- issue V fragment loads early: in flight across S+softmax chain
        bf16x8 vf[8];
#pragma unroll
        for (int dt = 0; dt < 8; ++dt)
            vf[dt] = __builtin_bit_cast(bf16x8, *(const uint4*)(vt_ + (dt << 9)));

        // ---- prefetch next tile's adjacency bias (non-temporal)
        float b0n[4], b1n[4];
        if (t < 15) {
            const int kn = h * 512 + (t + 1) * 32;
#pragma unroll
            for (int r = 0; r < 4; ++r) {
                b0n[r] = ld_nt(&adjb[(size_t)r * 2048 + kn + n])      ? 0.f : MB;
                b1n[r] = ld_nt(&adjb[(size_t)r * 2048 + kn + 16 + n]) ? 0.f : MB;
            }
        }

        // ---- S = Q K^T : 8 MFMA
        fx4 S0 = {0.f, 0.f, 0.f, 0.f}, S1 = {0.f, 0.f, 0.f, 0.f};
#pragma unroll
        for (int kk = 0; kk < 4; ++kk) {
            S0 = MFMA16(qf[kk], kb[kk], S0);
            S1 = MFMA16(qf[kk], kb[4 + kk], S1);
        }

        // ---- fixed-shift softmax numerator: p = exp2(S*C2 + bias)
#pragma unroll
        for (int r = 0; r < 4; ++r) {
            const float e0 = exp2_fast(__builtin_fmaf(S0[r], C2, b0c[r]));
            const float e1 = exp2_fast(__builtin_fmaf(S1[r], C2, b1c[r]));
            pw[(quad * 4 + r) * 40 + n]      = f2bf_fast(e0);
            pw[(quad * 4 + r) * 40 + 16 + n] = f2bf_fast(e1);
        }

        WAVE_LDS_SYNC();   // pl write -> read, wave-private
        bf16x8 pf = __builtin_bit_cast(bf16x8, *(const uint4*)&pw[n * 40 + quad * 8]);

        // ---- O += P V : 8 MFMA on prefetched V fragments
#pragma unroll
        for (int dt = 0; dt < 8; ++dt)
            O[dt] = MFMA16(pf, vf[dt], O[dt]);
        // ---- row sum of exactly-what-PV-sees: one MFMA, no shuffles
        Lacc = MFMA16(pf, ONESF, Lacc);

#pragma unroll
        for (int r = 0; r < 4; ++r) { b0c[r] = b0n[r]; b1c[r] = b1n[r]; }
    }

    // ---- 4-way merge across key-quarters (one barrier), ELU, store
#pragma unroll
    for (int r = 0; r < 4; ++r) {
        const int row = quad * 4 + r;
        if (n == 0) ml[h][row] = Lacc[r];
#pragma unroll
        for (int dt = 0; dt < 8; ++dt)
            mO[h][row * 128 + dt * 16 + n] = O[dt][r];
    }
    __syncthreads();

#pragma unroll
    for (int r = 0; r < 4; ++r) {
        const int row = quad * 4 + r;
        const float L = ml[0][row] + ml[1][row] + ml[2][row] + ml[3][row];
        const float linv = 1.f / L;
        float* po = out + (bN + q0 + row) * 128;
#pragma unroll
        for (int dti = 0; dti < 2; ++dti) {
            const int dt = h * 2 + dti;
            float o = 0.f;
#pragma unroll
            for (int g = 0; g < 4; ++g) o += mO[g][row * 128 + dt * 16 + n];
            const float hh = o * linv;
            po[dt * 16 + n] = (hh > 0.f) ? hh : (__expf(hh) - 1.f);
        }
    }
}

// ---------------------------------------------------------------------------
extern "C" void kernel_launch(void* const* d_in, const int* in_sizes, int n_in,
                              void* d_out, int out_size, void* d_ws, size_t ws_size,
                              hipStream_t stream) {
    (void)in_sizes; (void)n_in; (void)out_size; (void)ws_size;
    const float* X   = (const float*)d_in[0];
    const int*   adj = (const int*)d_in[1];
    const float* Wq  = (const float*)d_in[2];
    const float* bq  = (const float*)d_in[3];
    const float* Wk  = (const float*)d_in[4];
    const float* bk  = (const float*)d_in[5];
    const float* Wv  = (const float*)d_in[6];
    const float* bv  = (const float*)d_in[7];
    float* out = (float*)d_out;

    u16* WT  = (u16*)d_out;                      // 96 KB scratch, overwritten by attn
    u16* Qf  = (u16*)d_ws;                       // 4 MB fragment-major Q
    u16* Kf  = Qf + (size_t)16384 * 128;         // 4 MB fragment-major K
    u16* Vf  = Kf + (size_t)16384 * 128;         // 4 MB fragment-major V^T

    wt_kernel<<<192, 256, 0, stream>>>(Wq, Wk, Wv, WT);
    qkv_kernel<<<512, 256, 0, stream>>>(X, WT, bq, bk, bv, Qf, Kf, Vf);
    attn_kernel<<<1024, 256, 0, stream>>>(Qf, Kf, Vf, adj, out);
}

// Round 7
// 255.114 us; speedup vs baseline: 1.4480x; 1.1870x over previous
//
#include <hip/hip_runtime.h>

typedef unsigned short u16;
typedef unsigned int   u32;
typedef unsigned long long u64;
typedef __bf16 bf16x8 __attribute__((ext_vector_type(8)));
typedef float  fx4    __attribute__((ext_vector_type(4)));

__device__ __forceinline__ u16 f2bf(float f) {
    unsigned int x = __builtin_bit_cast(unsigned int, f);
    x = x + 0x7fffu + ((x >> 16) & 1u);   // round-to-nearest-even
    return (u16)(x >> 16);
}
__device__ __forceinline__ __bf16 f2bf16(float f) {
    return __builtin_bit_cast(__bf16, f2bf(f));
}
// native RNE f32->bf16
__device__ __forceinline__ u16 f2bf_fast(float f) {
    return __builtin_bit_cast(u16, (__bf16)f);
}
__device__ __forceinline__ float exp2_fast(float x) {
#if __has_builtin(__builtin_amdgcn_exp2f)
    return __builtin_amdgcn_exp2f(x);
#else
    float r;
    __asm__ volatile("v_exp_f32 %0, %1" : "=v"(r) : "v"(x));
    return r;
#endif
}
__device__ __forceinline__ int ld_nt(const int* p) {
    return __builtin_nontemporal_load(p);
}

#define MFMA16(a, b, c) __builtin_amdgcn_mfma_f32_16x16x32_bf16((a), (b), (c), 0, 0, 0)
// wave-private LDS write->read ordering (DS ops are in-order per wave)
#define WAVE_LDS_SYNC() __asm__ volatile("s_waitcnt lgkmcnt(0)" ::: "memory")

// ---------------------------------------------------------------------------
// Kernel A: WT[p][c][k] = bf16(W_p[k][c])  -> stored in first 96 KB of d_out
// ---------------------------------------------------------------------------
__global__ __launch_bounds__(256) void wt_kernel(
    const float* __restrict__ Wq, const float* __restrict__ Wk,
    const float* __restrict__ Wv, u16* __restrict__ WT)
{
    const int o = blockIdx.x * 256 + threadIdx.x;     // 0..49151
    const int p = o >> 14, rem = o & 16383, c = rem >> 7, k = rem & 127;
    const float* W = (p == 0) ? Wq : ((p == 1) ? Wk : Wv);
    WT[o] = f2bf(W[k * 128 + c]);
}

// ---------------------------------------------------------------------------
// Kernel A2: bit-pack adjacency via wave ballot. adj {0,1} int32 (128 MB) ->
// 1-bit mask (4 MB). Each wave-iter: 4 coalesced nt loads (lane-linear) ->
// 4 x __ballot (u64 with bit L = lane L's int, i.e. EXACT linear bit order)
// -> lanes 0-3 store 4 u64 covering 256 ints. No LDS, no cross-wave hazard.
// (Round-5 pack read OOB LDS -> wrong mask; this replaces it.)
// ---------------------------------------------------------------------------
__global__ __launch_bounds__(256) void pack_kernel(
    const int* __restrict__ adj, u64* __restrict__ mask64)
{
    const int w = threadIdx.x >> 6, lane = threadIdx.x & 63;
    const int gw = blockIdx.x * 4 + w;
    const int nw = gridDim.x * 4;
    // 8*2048*2048 ints = 32 Mi ints = 131072 iters of 256 ints
    for (int it = gw; it < 131072; it += nw) {
        const int* base = adj + (size_t)it * 256 + lane;
        const u64 b0 = __ballot(ld_nt(base +   0) != 0);
        const u64 b1 = __ballot(ld_nt(base +  64) != 0);
        const u64 b2 = __ballot(ld_nt(base + 128) != 0);
        const u64 b3 = __ballot(ld_nt(base + 192) != 0);
        if (lane < 4) {
            const u64 v = (lane == 0) ? b0 : (lane == 1) ? b1 : (lane == 2) ? b2 : b3;
            mask64[(size_t)it * 4 + lane] = v;
        }
    }
}

// ---------------------------------------------------------------------------
// Kernel B: Q, K, V^T fragment-major. Results staged per-wave in LDS in
// fragment layout (scattered 2-B LDS writes are cheap), then written to global
// with fully-coalesced uint4 stores instead of 48 scattered 2-B global stores.
// ---------------------------------------------------------------------------
__global__ __launch_bounds__(256, 2) void qkv_kernel(
    const float* __restrict__ X, const u16* __restrict__ WT,
    const float* __restrict__ bq, const float* __restrict__ bk,
    const float* __restrict__ bv,
    u16* __restrict__ Qf, u16* __restrict__ Kf, u16* __restrict__ Vf)
{
    __shared__ __align__(16) u16 st[4][1024];   // 2 KB per wave staging

    const int tid  = threadIdx.x;
    const int w    = tid >> 6;
    const int lane = tid & 63;
    const int n    = lane & 15;
    const int quad = lane >> 4;
    const int gw   = blockIdx.x * 4 + w;   // 0..2047
    const int rt   = gw >> 1, ch = gw & 1;
    const int row0 = rt * 16;
    const int b    = row0 >> 11;
    const int keyb = row0 & 2047;          // multiple of 16

    u16* sw = st[w];

    // X fragments: lane holds X[row0+n][kk*32 + quad*8 + j]  (fp32 -> bf16).
    bf16x8 af[4];
    {
        const float* xr = X + (size_t)(row0 + n) * 128;
#pragma unroll
        for (int kk = 0; kk < 4; ++kk) {
            float4 f0 = *(const float4*)(xr + kk * 32 + quad * 8);
            float4 f1 = *(const float4*)(xr + kk * 32 + quad * 8 + 4);
            bf16x8 a;
            a[0] = f2bf16(f0.x); a[1] = f2bf16(f0.y); a[2] = f2bf16(f0.z); a[3] = f2bf16(f0.w);
            a[4] = f2bf16(f1.x); a[5] = f2bf16(f1.y); a[6] = f2bf16(f1.z); a[7] = f2bf16(f1.w);
            af[kk] = a;
        }
    }

    // ---- Q and K (LDS-staged, coalesced store)
    const float* Bs[2] = {bq, bk};
#pragma unroll
    for (int p = 0; p < 2; ++p) {
        const u16* wt = WT + p * 16384;
#pragma unroll
        for (int nt = 0; nt < 4; ++nt) {
            const int col0 = ch * 64 + nt * 16;
            fx4 acc = {0.f, 0.f, 0.f, 0.f};
#pragma unroll
            for (int kk = 0; kk < 4; ++kk) {
                bf16x8 bf = __builtin_bit_cast(bf16x8,
                    *(const uint4*)&wt[(col0 + n) * 128 + kk * 32 + quad * 8]);
                acc = MFMA16(af[kk], bf, acc);
            }
            const float bb = Bs[p][col0 + n];
            const int c = col0 + n;
            // local fragment index within this wave's 1024-u16 span
            const int li = ((c >> 5) & 1) * 512 + ((c >> 3) & 3) * 128 + (c & 7);
#pragma unroll
            for (int r = 0; r < 4; ++r)
                sw[li + (quad * 4 + r) * 8] = f2bf(acc[r] + bb);
        }
        WAVE_LDS_SYNC();
        u16* gbase;
        if (p == 0) {
            gbase = Qf + (((size_t)(b * 128 + (keyb >> 4)) * 4 + 2 * ch) << 9);
        } else {
            gbase = Kf + (((size_t)((b * 64 + (keyb >> 5)) * 2 + ((keyb >> 4) & 1)) * 4 + 2 * ch) << 9);
        }
        *(uint4*)(gbase + lane * 8)       = *(const uint4*)(sw + lane * 8);
        *(uint4*)(gbase + 512 + lane * 8) = *(const uint4*)(sw + 512 + lane * 8);
    }

    // ---- V^T[d][key]  (operand-swapped MFMA), LDS-staged
    {
        const u16* wtv = WT + 2 * 16384;
        const int hk    = (keyb >> 4) & 1;
        const int vtile = keyb >> 5;
#pragma unroll
        for (int d0 = 0; d0 < 4; ++d0) {
            const int dbase = ch * 64 + d0 * 16;
            fx4 acc = {0.f, 0.f, 0.f, 0.f};
#pragma unroll
            for (int kk = 0; kk < 4; ++kk) {
                bf16x8 wf = __builtin_bit_cast(bf16x8,
                    *(const uint4*)&wtv[(dbase + n) * 128 + kk * 32 + quad * 8]);
                acc = MFMA16(wf, af[kk], acc);
            }
            const int li = d0 * 256 + ((n >> 3) & 1) * 128 + (n & 7);
#pragma unroll
            for (int r = 0; r < 4; ++r)
                sw[li + (quad * 4 + r) * 8] = f2bf(acc[r] + bv[dbase + quad * 4 + r]);
        }
        WAVE_LDS_SYNC();
        const int l5 = lane >> 5, lo = lane & 31;
#pragma unroll
        for (int i = 0; i < 2; ++i) {
            const int c2 = l5 + 2 * i;
            u16* g = Vf + (((size_t)(b * 64 + vtile) * 8 + ch * 4 + c2) << 9)
                        + hk * 256 + lo * 8;
            *(uint4*)g = *(const uint4*)(sw + c2 * 256 + lo * 8);
        }
    }
}

// ---------------------------------------------------------------------------
// Kernel C: fused masked attention, fixed-shift softmax. Round-1 structure
// (proven 92 us) with the in-loop adjacency reads (8 scalar int loads/tile
// from the 128 MB HBM stream -> ~900-cycle latency stalls) replaced by 4 u32
// loads/tile from the 4 MB L2-resident bitmask, prefetched one tile ahead.
// ---------------------------------------------------------------------------
__global__ __launch_bounds__(256, 4) void attn_kernel(
    const u16* __restrict__ Qf, const u16* __restrict__ Kf,
    const u16* __restrict__ Vf, const u32* __restrict__ mask,
    float* __restrict__ out)
{
    __shared__ __align__(16) float mO[4][16 * 128];  // per-wave O dump (32 KB)
    __shared__ __align__(16) float ml[4][16];        // per-wave row sums
    __shared__ __align__(16) u16 pl[4][640];         // per-wave P, stride 40

    const int tid  = threadIdx.x;
    const int h    = tid >> 6;                       // key-quarter
    const int lane = tid & 63;
    const int n    = lane & 15;
    const int quad = lane >> 4;
    const int b    = blockIdx.x & 7;
    const int qt   = blockIdx.x >> 3;                // 0..127
    const int q0   = qt * 16;
    const size_t bN = (size_t)b * 2048;

    // Q fragments (A-layout): 4 coalesced 1 KB loads
    bf16x8 qf[4];
    {
        const u16* qp = Qf + ((size_t)(b * 128 + qt) << 11) + lane * 8;
#pragma unroll
        for (int kk = 0; kk < 4; ++kk)
            qf[kk] = __builtin_bit_cast(bf16x8, *(const uint4*)(qp + (kk << 9)));
    }
    const u16* Kb = Kf + ((size_t)b << 18);
    const u16* Vb = Vf + ((size_t)b << 18);

    fx4 O[8];
#pragma unroll
    for (int i = 0; i < 8; ++i) O[i] = (fx4){0.f, 0.f, 0.f, 0.f};
    fx4 Lacc = {0.f, 0.f, 0.f, 0.f};                 // row sums via MFMA-ones

    bf16x8 ONESF;
    {
        const __bf16 one = __builtin_bit_cast(__bf16, (u16)0x3F80);
#pragma unroll
        for (int j = 0; j < 8; ++j) ONESF[j] = one;
    }

    // bitmask base for this wave's 4 rows (64 u32 words per row)
    const u32* mrow = mask + (bN + q0 + quad * 4) * 64 + h * 16;
    const float C2 = 0.12751742f;   // (1/sqrt(128)) * log2(e)
    const float MB = -14427.0f;     // -10000 * log2(e): exp2 -> exactly 0.0
    u16* pw = pl[h];

    // prologue: mask words for first tile
    u32 mc[4];
#pragma unroll
    for (int r = 0; r < 4; ++r) mc[r] = mrow[r * 64];

    for (int t = 0; t < 16; ++t) {
        const int tg = h * 16 + t;
        const u16* kt_ = Kb + ((size_t)tg << 12) + lane * 8;
        const u16* vt_ = Vb + ((size_t)tg << 12) + lane * 8;

        // ---- issue K fragment loads first (S-chain head)
        bf16x8 kb[8];
#pragma unroll
        for (int kk = 0; kk < 8; ++kk)
            kb[kk] = __builtin_bit_cast(bf16x8, *(const uint4*)(kt_ + (kk << 9)));

        // ---- issue V fragment loads early: in flight across S+softmax chain
        bf16x8 vf[8];
#pragma unroll
        for (int dt = 0; dt < 8; ++dt)
            vf[dt] = __builtin_bit_cast(bf16x8, *(const uint4*)(vt_ + (dt << 9)));

        // ---- prefetch next tile's mask words (L2-resident, 4 B each)
        u32 mn_[4];
        if (t < 15) {
#pragma unroll
            for (int r = 0; r < 4; ++r) mn_[r] = mrow[r * 64 + t + 1];
        }

        // ---- S = Q K^T : 8 MFMA
        fx4 S0 = {0.f, 0.f, 0.f, 0.f}, S1 = {0.f, 0.f, 0.f, 0.f};
#pragma unroll
        for (int kk = 0; kk < 4; ++kk) {
            S0 = MFMA16(qf[kk], kb[kk], S0);
            S1 = MFMA16(qf[kk], kb[4 + kk], S1);
        }

        // ---- fixed-shift softmax numerator: p = exp2(S*C2 + bias)
#pragma unroll
        for (int r = 0; r < 4; ++r) {
            const float bias0 = ((mc[r] >> n) & 1u)        ? 0.f : MB;
            const float bias1 = ((mc[r] >> (16 + n)) & 1u) ? 0.f : MB;
            const float e0 = exp2_fast(__builtin_fmaf(S0[r], C2, bias0));
            const float e1 = exp2_fast(__builtin_fmaf(S1[r], C2, bias1));
            pw[(quad * 4 + r) * 40 + n]      = f2bf_fast(e0);
            pw[(quad * 4 + r) * 40 + 16 + n] = f2bf_fast(e1);
        }

        WAVE_LDS_SYNC();   // pl write -> read, wave-private
        bf16x8 pf = __builtin_bit_cast(bf16x8, *(const uint4*)&pw[n * 40 + quad * 8]);

        // ---- O += P V : 8 MFMA on prefetched V fragments
#pragma unroll
        for (int dt = 0; dt < 8; ++dt)
            O[dt] = MFMA16(pf, vf[dt], O[dt]);
        // ---- row sum of exactly-what-PV-sees: one MFMA, no shuffles
        Lacc = MFMA16(pf, ONESF, Lacc);

#pragma unroll
        for (int r = 0; r < 4; ++r) mc[r] = mn_[r];
    }

    // ---- 4-way merge across key-quarters (one barrier), ELU, store
#pragma unroll
    for (int r = 0; r < 4; ++r) {
        const int row = quad * 4 + r;
        if (n == 0) ml[h][row] = Lacc[r];
#pragma unroll
        for (int dt = 0; dt < 8; ++dt)
            mO[h][row * 128 + dt * 16 + n] = O[dt][r];
    }
    __syncthreads();

#pragma unroll
    for (int r = 0; r < 4; ++r) {
        const int row = quad * 4 + r;
        const float L = ml[0][row] + ml[1][row] + ml[2][row] + ml[3][row];
        const float linv = 1.f / L;
        float* po = out + (bN + q0 + row) * 128;
#pragma unroll
        for (int dti = 0; dti < 2; ++dti) {
            const int dt = h * 2 + dti;
            float o = 0.f;
#pragma unroll
            for (int g = 0; g < 4; ++g) o += mO[g][row * 128 + dt * 16 + n];
            const float hh = o * linv;
            po[dt * 16 + n] = (hh > 0.f) ? hh : (__expf(hh) - 1.f);
        }
    }
}

// ---------------------------------------------------------------------------
extern "C" void kernel_launch(void* const* d_in, const int* in_sizes, int n_in,
                              void* d_out, int out_size, void* d_ws, size_t ws_size,
                              hipStream_t stream) {
    (void)in_sizes; (void)n_in; (void)out_size; (void)ws_size;
    const float* X   = (const float*)d_in[0];
    const int*   adj = (const int*)d_in[1];
    const float* Wq  = (const float*)d_in[2];
    const float* bq  = (const float*)d_in[3];
    const float* Wk  = (const float*)d_in[4];
    const float* bk  = (const float*)d_in[5];
    const float* Wv  = (const float*)d_in[6];
    const float* bv  = (const float*)d_in[7];
    float* out = (float*)d_out;

    u16* WT   = (u16*)d_out;                     // 96 KB scratch, overwritten by attn
    u16* Qf   = (u16*)d_ws;                      // 4 MB fragment-major Q
    u16* Kf   = Qf + (size_t)16384 * 128;        // 4 MB fragment-major K
    u16* Vf   = Kf + (size_t)16384 * 128;        // 4 MB fragment-major V^T
    u32* mask = (u32*)(Vf + (size_t)16384 * 128);// 4 MB adjacency bitmask

    wt_kernel<<<192, 256, 0, stream>>>(Wq, Wk, Wv, WT);
    qkv_kernel<<<512, 256, 0, stream>>>(X, WT, bq, bk, bv, Qf, Kf, Vf);
    pack_kernel<<<2048, 256, 0, stream>>>(adj, (u64*)mask);
    attn_kernel<<<1024, 256, 0, stream>>>(Qf, Kf, Vf, mask, out);
}